// Round 17
// baseline (201.783 us; speedup 1.0000x reference)
//
#include <hip/hip_runtime.h>

#define NN 100000
#define NE 1600000
#define ET (NE + NN)
#define NB 391          // buckets of 256 dst nodes
#define CAP 5120        // slots/bucket (mean 4352, +12 sigma)
#define BST 16          // bcnt pad: 64B per counter
#define NBIN 512        // 2 blocks per CU: halves per-thread serial chunk chain
#define NCHK (ET/8)     // 212500 8-edge chunks; NE/8 = 200000 boundary
#define NTILE (NN/16)   // 6250 gemm tiles
#define NBG 1563        // gemm blocks inside k_bg: 1 tile per wave (6252 waves)

typedef _Float16 f16;
typedef __attribute__((ext_vector_type(8))) _Float16 half8;
typedef __attribute__((ext_vector_type(4))) float f32x4;

__device__ __forceinline__ unsigned short hbits(float v){
    f16 h = (f16)v;
    return *(unsigned short*)&h;
}
// pack 2 f32 -> 2 f16 (round-to-zero) in one v_cvt_pk_rtz instruction
__device__ __forceinline__ unsigned pk16(float a, float b){
    auto p = __builtin_amdgcn_cvt_pkrtz(a, b);   // __fp16 ext_vector(2)
    return *(unsigned*)&p;
}
__device__ __forceinline__ float fast_tanh(float x){
    float e = __expf(2.f*x);
    return 1.f - __fdividef(2.f, e + 1.f);
}
// acc_lo += f16(lo half of h2) * a ; acc_hi += f16(hi half of h2) * a
__device__ __forceinline__ void fmix2(float& al, float& ah, unsigned h2, float a){
    asm("v_fma_mix_f32 %0, %2, %3, %0 op_sel_hi:[1,0,0]\n\t"
        "v_fma_mix_f32 %1, %2, %3, %1 op_sel:[1,0,0] op_sel_hi:[1,0,0]"
        : "+v"(al), "+v"(ah) : "v"(h2), "v"(a));
}

// ---------------- pre: w2v = {W2@a_src2, W2@a_dst2, W2@Wl} + zero bcnt ----------------
__global__ void __launch_bounds__(256) k_pre2(const float* __restrict__ W2,
        const float* __restrict__ as2, const float* __restrict__ ad2,
        const float* __restrict__ Wl, float* __restrict__ w2v,
        int* __restrict__ bcnt){
    int t = threadIdx.x;
    if(t < 64){
        float s = 0.f, d = 0.f, g = 0.f;
        #pragma unroll 8
        for(int i=0;i<64;i++){
            float w = W2[t*64 + i];
            s += w*as2[i]; d += w*ad2[i]; g += w*Wl[i];
        }
        w2v[t] = s; w2v[64+t] = d; w2v[128+t] = g;
    }
    for(int i=t;i<NB*BST;i+=256) bcnt[i] = 0;
}

// ---------------- CSR build: bin by dst>>8, vectorized chunk loads ----------------
__global__ void __launch_bounds__(256) k_bin(const int* __restrict__ src,
        const int* __restrict__ dst, int* __restrict__ bcnt,
        int* __restrict__ binbuf){
    __shared__ int cnt[NB];
    __shared__ int cur[NB];
    int t = threadIdx.x;
    for(int i=t;i<NB;i+=256) cnt[i]=0;
    __syncthreads();
    // phase 1: histogram (vector loads of dst)
    for(int g = blockIdx.x*256 + t; g < NCHK; g += NBIN*256){
        if(g < NE/8){
            const uint4* dp = (const uint4*)(dst + g*8);
            uint4 d0 = dp[0], d1 = dp[1];
            atomicAdd(&cnt[d0.x>>8],1); atomicAdd(&cnt[d0.y>>8],1);
            atomicAdd(&cnt[d0.z>>8],1); atomicAdd(&cnt[d0.w>>8],1);
            atomicAdd(&cnt[d1.x>>8],1); atomicAdd(&cnt[d1.y>>8],1);
            atomicAdd(&cnt[d1.z>>8],1); atomicAdd(&cnt[d1.w>>8],1);
        } else {
            int n0 = g*8 - NE;        // 8 consecutive self-loops
            #pragma unroll
            for(int i=0;i<8;i++) atomicAdd(&cnt[(n0+i)>>8],1);
        }
    }
    __syncthreads();
    // phase 2: one global reservation per bucket
    for(int i=t;i<NB;i+=256){ int c=cnt[i]; cur[i] = c ? atomicAdd(&bcnt[i*BST], c) : 0; }
    __syncthreads();
    // phase 3: scatter into reserved runs (vector loads of src+dst)
    for(int g = blockIdx.x*256 + t; g < NCHK; g += NBIN*256){
        int s[8], d[8];
        if(g < NE/8){
            const uint4* sp = (const uint4*)(src + g*8);
            const uint4* dp = (const uint4*)(dst + g*8);
            uint4 s0 = sp[0], s1 = sp[1];
            uint4 d0 = dp[0], d1 = dp[1];
            s[0]=s0.x; s[1]=s0.y; s[2]=s0.z; s[3]=s0.w;
            s[4]=s1.x; s[5]=s1.y; s[6]=s1.z; s[7]=s1.w;
            d[0]=d0.x; d[1]=d0.y; d[2]=d0.z; d[3]=d0.w;
            d[4]=d1.x; d[5]=d1.y; d[6]=d1.z; d[7]=d1.w;
        } else {
            int n0 = g*8 - NE;
            #pragma unroll
            for(int i=0;i<8;i++){ s[i]=n0+i; d[i]=n0+i; }
        }
        #pragma unroll
        for(int i=0;i<8;i++){
            int b = d[i] >> 8;
            int pos = atomicAdd(&cur[b], 1);
            if(pos < CAP) binbuf[b*CAP + pos] = (s[i] << 8) | (d[i] & 255);
        }
    }
}

// ---------------- fused: per-bucket dense CSR build (blocks 0..NB-1)
//                  + layer-1 gemm h=x@W1, ssrc, sdst (blocks NB..NB+NBG-1) ----
__global__ void __launch_bounds__(256) k_bg(
        const int* __restrict__ bcnt, const int* __restrict__ binbuf,
        int* __restrict__ edge_src, int2* __restrict__ rd,
        const float* __restrict__ xin, const float* __restrict__ W,
        const float* __restrict__ avs, const float* __restrict__ avd,
        f16* __restrict__ hb, float* __restrict__ ssrc,
        float* __restrict__ sdst){
    __shared__ int lsrc[CAP];
    __shared__ int ldeg[256], lscan[256], lcur[256], red[256];
    int t = threadIdx.x;
    if(blockIdx.x < NB){
        // ---------- CSR build path ----------
        int b = blockIdx.x;
        int cnt = min(bcnt[b*BST], CAP);
        int part = 0;
        for(int i=t;i<b;i+=256) part += min(bcnt[i*BST], CAP);
        red[t] = part; __syncthreads();
        for(int off=128; off>=1; off>>=1){ if(t<off) red[t]+=red[t+off]; __syncthreads(); }
        int base = red[0];
        __syncthreads();
        ldeg[t] = 0; __syncthreads();
        const int* bb = binbuf + b*CAP;
        for(int i=t;i<cnt;i+=256) atomicAdd(&ldeg[bb[i] & 255], 1);
        __syncthreads();
        int dv = ldeg[t]; lscan[t] = dv; __syncthreads();
        for(int off=1; off<256; off<<=1){
            int u = (t>=off) ? lscan[t-off] : 0;
            __syncthreads(); lscan[t] += u; __syncthreads();
        }
        int excl = lscan[t] - dv; lcur[t] = excl;
        int node = b*256 + t;
        if(node < NN) rd[node] = make_int2(base + excl, dv);
        __syncthreads();
        for(int i=t;i<cnt;i+=256){
            int ent = bb[i];
            int pos = atomicAdd(&lcur[ent & 255], 1);
            lsrc[pos] = ent >> 8;
        }
        __syncthreads();
        for(int i=t;i<cnt;i+=256) edge_src[base+i] = lsrc[i];
    } else {
        // ---------- layer-1 gemm path (fp32 input, f16 MFMA), 1 tile/wave ----------
        int lane = t & 63;
        int col = lane & 15, q = lane >> 4;
        half8 Bf[2][4];
        #pragma unroll
        for(int kh=0;kh<2;kh++){
            #pragma unroll
            for(int nb=0;nb<4;nb++){
                half8 bfr;
                #pragma unroll
                for(int j=0;j<8;j++){
                    float w = W[(kh*32 + q*8 + j)*64 + nb*16 + col];
                    bfr[j] = (f16)w;
                }
                Bf[kh][nb] = bfr;
            }
        }
        float as[4], ad[4];
        #pragma unroll
        for(int nb=0;nb<4;nb++){ as[nb] = avs[nb*16+col]; ad[nb] = avd[nb*16+col]; }

        int gw = ((blockIdx.x - NB)*256 + t) >> 6;
        int nwaves = NBG*4;
        for(int tile = gw; tile < NTILE; tile += nwaves){
            int n0 = tile*16;
            f32x4 acc[4];
            #pragma unroll
            for(int nb=0;nb<4;nb++) acc[nb] = (f32x4){0.f,0.f,0.f,0.f};
            #pragma unroll
            for(int kh=0;kh<2;kh++){
                const float4* xr = (const float4*)(xin
                                    + (size_t)(n0+col)*64 + kh*32 + q*8);
                float4 u = xr[0], v = xr[1];
                union { half8 h; uint4 u4; } A;
                A.u4.x = pk16(u.x, u.y);
                A.u4.y = pk16(u.z, u.w);
                A.u4.z = pk16(v.x, v.y);
                A.u4.w = pk16(v.z, v.w);
                #pragma unroll
                for(int nb=0;nb<4;nb++)
                    acc[nb] = __builtin_amdgcn_mfma_f32_16x16x32_f16(A.h, Bf[kh][nb], acc[nb], 0,0,0);
            }
            #pragma unroll
            for(int nb=0;nb<4;nb++){
                #pragma unroll
                for(int r=0;r<4;r++)
                    hb[(size_t)(n0 + q*4 + r)*64 + nb*16 + col] = (f16)acc[nb][r];
            }
            #pragma unroll
            for(int r=0;r<4;r++){
                float ps = acc[0][r]*as[0] + acc[1][r]*as[1] + acc[2][r]*as[2] + acc[3][r]*as[3];
                float pd = acc[0][r]*ad[0] + acc[1][r]*ad[1] + acc[2][r]*ad[2] + acc[3][r]*ad[3];
                #pragma unroll
                for(int m=8;m>=1;m>>=1){ ps += __shfl_xor(ps,m); pd += __shfl_xor(pd,m); }
                if(col == 0){ ssrc[n0 + q*4 + r] = ps; sdst[n0 + q*4 + r] = pd; }
            }
        }
    }
}

// ---------------- full-wave fallback (layer 1): one node, any degree ----------------
__device__ __forceinline__ void node_full1(int node, int lane, int2* lp,
        const int2* __restrict__ rd, const int* __restrict__ edge_src,
        const float* __restrict__ ssrc, const float* __restrict__ sdst,
        const f16* __restrict__ hb, const float* __restrict__ bias,
        const float* __restrict__ w2v, float* __restrict__ ssrc2,
        float* __restrict__ sdst2, float* __restrict__ gsc){
    int2 r = rd[node];
    int rs = r.x, d = r.y;
    float sd = sdst[node];
    int g8 = lane >> 3;
    int c  = lane & 7;
    float a0=0.f,a1=0.f,a2=0.f,a3=0.f,a4=0.f,a5=0.f,a6=0.f,a7=0.f;

    float lmax = -1e30f;
    for(int j=lane; j<d; j+=64){
        int sj = edge_src[rs+j];
        float t = ssrc[sj] + sd;
        lmax = fmaxf(lmax, fmaxf(t, 0.2f*t));
    }
    #pragma unroll
    for(int m=32;m>=1;m>>=1) lmax = fmaxf(lmax, __shfl_xor(lmax,m));
    float lsum = 0.f;
    for(int j=lane; j<d; j+=64){
        int sj = edge_src[rs+j];
        float t = ssrc[sj] + sd;
        lsum += __expf(fmaxf(t, 0.2f*t) - lmax);
    }
    #pragma unroll
    for(int m=32;m>=1;m>>=1) lsum += __shfl_xor(lsum,m);
    float inv = 1.0f/(lsum + 1e-16f);
    for(int cb=0; cb<d; cb+=64){
        int s2 = 0; float al = 0.f;
        int j = cb + lane;
        if(j < d){
            s2 = edge_src[rs+j];
            float t = ssrc[s2] + sd;
            al = __expf(fmaxf(t, 0.2f*t) - lmax) * inv;
        }
        lp[lane] = make_int2(__float_as_int(al), s2);
        int dd = min(d - cb, 64);
        for(int i0=0; i0<dd; i0+=16){
            int2 e0 = lp[i0 + g8];
            int2 e1 = lp[i0 + 8 + g8];
            float f0 = __int_as_float(e0.x);
            float f1 = __int_as_float(e1.x);
            uint4 k0 = *(const uint4*)(hb + ((size_t)e0.y<<6) + (c<<3));
            uint4 k1 = *(const uint4*)(hb + ((size_t)e1.y<<6) + (c<<3));
            fmix2(a0,a1,k0.x,f0); fmix2(a2,a3,k0.y,f0);
            fmix2(a4,a5,k0.z,f0); fmix2(a6,a7,k0.w,f0);
            fmix2(a0,a1,k1.x,f1); fmix2(a2,a3,k1.y,f1);
            fmix2(a4,a5,k1.z,f1); fmix2(a6,a7,k1.w,f1);
        }
    }
    #pragma unroll
    for(int m=32;m>=8;m>>=1){
        a0 += __shfl_xor(a0,m); a1 += __shfl_xor(a1,m);
        a2 += __shfl_xor(a2,m); a3 += __shfl_xor(a3,m);
        a4 += __shfl_xor(a4,m); a5 += __shfl_xor(a5,m);
        a6 += __shfl_xor(a6,m); a7 += __shfl_xor(a7,m);
    }
    const float4* bp = (const float4*)bias;
    float4 bv0 = bp[c*2], bv1 = bp[c*2+1];
    float t0 = fast_tanh(a0+bv0.x), t1 = fast_tanh(a1+bv0.y);
    float t2 = fast_tanh(a2+bv0.z), t3 = fast_tanh(a3+bv0.w);
    float t4 = fast_tanh(a4+bv1.x), t5 = fast_tanh(a5+bv1.y);
    float t6 = fast_tanh(a6+bv1.z), t7 = fast_tanh(a7+bv1.w);
    const float4* vs = (const float4*)(w2v);
    const float4* vd = (const float4*)(w2v+64);
    const float4* vg = (const float4*)(w2v+128);
    float4 s0 = vs[c*2], s1 = vs[c*2+1];
    float4 d0 = vd[c*2], d1 = vd[c*2+1];
    float4 g0 = vg[c*2], g1 = vg[c*2+1];
    float q_s = t0*s0.x+t1*s0.y+t2*s0.z+t3*s0.w + t4*s1.x+t5*s1.y+t6*s1.z+t7*s1.w;
    float q_d = t0*d0.x+t1*d0.y+t2*d0.z+t3*d0.w + t4*d1.x+t5*d1.y+t6*d1.z+t7*d1.w;
    float q_g = t0*g0.x+t1*g0.y+t2*g0.z+t3*g0.w + t4*g1.x+t5*g1.y+t6*g1.z+t7*g1.w;
    #pragma unroll
    for(int m=4;m>=1;m>>=1){
        q_s += __shfl_xor(q_s,m); q_d += __shfl_xor(q_d,m); q_g += __shfl_xor(q_g,m);
    }
    if(lane == 0){ ssrc2[node] = q_s; sdst2[node] = q_d; gsc[node] = q_g; }
}

// ---------------- layer-1 aggregation: 2 nodes per wave ----------------
__global__ void __launch_bounds__(256) k_agg1(
        const int2* __restrict__ rd, const int* __restrict__ edge_src,
        const float* __restrict__ ssrc, const float* __restrict__ sdst,
        const f16* __restrict__ hb, const float* __restrict__ bias,
        const float* __restrict__ w2v, float* __restrict__ ssrc2,
        float* __restrict__ sdst2, float* __restrict__ gsc){
    __shared__ int2 pairs[256];
    int tid = threadIdx.x;
    int wv   = (blockIdx.x*256 + tid) >> 6;   // wave id: 0..NN/2-1
    int lane = tid & 63;
    if(wv*2 >= NN) return;
    int2* lp = pairs + (tid & 192);           // wave-private 64-entry table
    int half = lane >> 5, l = lane & 31;
    int node = wv*2 + half;

    int2 r = rd[node];
    int rs = r.x, d = r.y;
    float sd = sdst[node];
    int dmax = max(d, __shfl_xor(d, 32));

    if(dmax <= 32){
        // ---- per-half softmax ----
        int s = 0; float pr = 0.f;
        if(l < d){
            s = edge_src[rs + l];
            float t = ssrc[s] + sd;
            t = fmaxf(t, 0.2f*t);            // leaky_relu
            pr = __expf(fminf(t, 80.f));     // no max-shift: logits O(10)
        }
        float sm = pr;
        #pragma unroll
        for(int m=16;m>=1;m>>=1) sm += __shfl_xor(sm,m);
        float alpha = pr * (1.0f/(sm + 1e-16f));
        lp[lane] = make_int2(__float_as_int(alpha), s);   // lane = half*32+l

        // ---- gather: batch-issue ALL loads, then all FMAs ----
        int g4 = l >> 3;                     // row-group 0..3
        int c  = l & 7;                      // channel chunk
        int base = half << 5;
        int nitw = (dmax + 7) >> 3;          // 1..4, wave-uniform
        float F0[4], F1[4];
        uint4 K0[4], K1[4];
        #pragma unroll
        for(int it=0; it<4; it++){
            if(it < nitw){
                int2 e0 = lp[base + it*8 + g4];
                int2 e1 = lp[base + it*8 + 4 + g4];
                F0[it] = __int_as_float(e0.x);
                F1[it] = __int_as_float(e1.x);
                K0[it] = *(const uint4*)(hb + ((size_t)e0.y<<6) + (c<<3));
                K1[it] = *(const uint4*)(hb + ((size_t)e1.y<<6) + (c<<3));
            }
        }
        float a0=0.f,a1=0.f,a2=0.f,a3=0.f,a4=0.f,a5=0.f,a6=0.f,a7=0.f;
        #pragma unroll
        for(int it=0; it<4; it++){
            if(it < nitw){
                fmix2(a0,a1,K0[it].x,F0[it]); fmix2(a2,a3,K0[it].y,F0[it]);
                fmix2(a4,a5,K0[it].z,F0[it]); fmix2(a6,a7,K0[it].w,F0[it]);
                fmix2(a0,a1,K1[it].x,F1[it]); fmix2(a2,a3,K1[it].y,F1[it]);
                fmix2(a4,a5,K1[it].z,F1[it]); fmix2(a6,a7,K1[it].w,F1[it]);
            }
        }

        // ---- channel-splitting fold over row-groups (lane bits 3,4) ----
        bool b3 = (l >> 3) & 1, b4 = (l >> 4) & 1;
        float u0 = b3 ? a4 : a0, v0 = b3 ? a0 : a4; u0 += __shfl_xor(v0, 8);
        float u1 = b3 ? a5 : a1, v1 = b3 ? a1 : a5; u1 += __shfl_xor(v1, 8);
        float u2 = b3 ? a6 : a2, v2 = b3 ? a2 : a6; u2 += __shfl_xor(v2, 8);
        float u3 = b3 ? a7 : a3, v3 = b3 ? a3 : a7; u3 += __shfl_xor(v3, 8);
        float w0 = b4 ? u2 : u0, z0 = b4 ? u0 : u2; w0 += __shfl_xor(z0, 16);
        float w1 = b4 ? u3 : u1, z1 = b4 ? u1 : u3; w1 += __shfl_xor(z1, 16);
        int ch0 = (c<<3) + ((int)b3<<2) + ((int)b4<<1);   // even; w1 = ch0+1

        // ---- epilogue: tanh + layer-2 scalar dots (replaces t1 store) ----
        float2 bv = ((const float2*)bias)[ch0>>1];
        float tw0 = fast_tanh(w0 + bv.x), tw1 = fast_tanh(w1 + bv.y);
        float2 vs = ((const float2*)(w2v      ))[ch0>>1];
        float2 vd = ((const float2*)(w2v +  64))[ch0>>1];
        float2 vg = ((const float2*)(w2v + 128))[ch0>>1];
        float q_s = tw0*vs.x + tw1*vs.y;
        float q_d = tw0*vd.x + tw1*vd.y;
        float q_g = tw0*vg.x + tw1*vg.y;
        #pragma unroll
        for(int m=16;m>=1;m>>=1){
            q_s += __shfl_xor(q_s,m); q_d += __shfl_xor(q_d,m); q_g += __shfl_xor(q_g,m);
        }
        if(l == 0){ ssrc2[node] = q_s; sdst2[node] = q_d; gsc[node] = q_g; }
    } else {
        // rare: a node with d>32 in this pair -> full-wave generic, twice
        node_full1(wv*2,   lane, lp, rd, edge_src, ssrc, sdst, hb, bias,
                   w2v, ssrc2, sdst2, gsc);
        node_full1(wv*2+1, lane, lp, rd, edge_src, ssrc, sdst, hb, bias,
                   w2v, ssrc2, sdst2, gsc);
    }
}

// ---------------- layer-2 aggregation: scalar ----------------
// out[n] = (sum_j pr_j * g[s_j]) / (sum_j pr_j) + (b2.Wl + bl)
__global__ void __launch_bounds__(256) k_agg2(
        const int2* __restrict__ rd, const int* __restrict__ edge_src,
        const float* __restrict__ ssrc, const float* __restrict__ sdst,
        const float* __restrict__ gsc, const float* __restrict__ bias,
        const float* __restrict__ Wl, const float* __restrict__ bl,
        float* __restrict__ outF){
    int tid = threadIdx.x;
    int wv   = (blockIdx.x*256 + tid) >> 6;
    int lane = tid & 63;
    if(wv*2 >= NN) return;
    int half = lane >> 5, l = lane & 31;
    int node = wv*2 + half;

    // c2 = b2.Wl, computed cooperatively (lane l covers channels 2l, 2l+1)
    float2 bv = ((const float2*)bias)[l];
    float2 wl = ((const float2*)Wl)[l];
    float rc = bv.x*wl.x + bv.y*wl.y;
    #pragma unroll
    for(int m=16;m>=1;m>>=1) rc += __shfl_xor(rc,m);

    int2 r = rd[node];
    int rs = r.x, d = r.y;
    float sd = sdst[node];
    int dmax = max(d, __shfl_xor(d, 32));

    if(dmax <= 32){
        float pr = 0.f, gv = 0.f;
        if(l < d){
            int s = edge_src[rs + l];
            float t = ssrc[s] + sd;
            t = fmaxf(t, 0.2f*t);
            pr = __expf(fminf(t, 80.f));
            gv = gsc[s];
        }
        float sm = pr, num = pr*gv;
        #pragma unroll
        for(int m=16;m>=1;m>>=1){ sm += __shfl_xor(sm,m); num += __shfl_xor(num,m); }
        if(l == 0) outF[node] = num/(sm + 1e-16f) + rc + bl[0];
    } else {
        // rare: full-wave generic with max-shift, both nodes sequentially
        #pragma unroll 1
        for(int k=0;k<2;k++){
            int nd = wv*2 + k;
            int2 r2 = rd[nd];
            int rs2 = r2.x, d2 = r2.y;
            float sd2 = sdst[nd];
            float lmax = -1e30f;
            for(int j=lane; j<d2; j+=64){
                int sj = edge_src[rs2+j];
                float t = ssrc[sj] + sd2;
                lmax = fmaxf(lmax, fmaxf(t, 0.2f*t));
            }
            #pragma unroll
            for(int m=32;m>=1;m>>=1) lmax = fmaxf(lmax, __shfl_xor(lmax,m));
            float lsum = 0.f, lnum = 0.f;
            for(int j=lane; j<d2; j+=64){
                int sj = edge_src[rs2+j];
                float t = ssrc[sj] + sd2;
                float e = __expf(fmaxf(t, 0.2f*t) - lmax);
                lsum += e; lnum += e*gsc[sj];
            }
            #pragma unroll
            for(int m=32;m>=1;m>>=1){ lsum += __shfl_xor(lsum,m); lnum += __shfl_xor(lnum,m); }
            if(lane == 0) outF[nd] = lnum/(lsum + 1e-16f) + rc + bl[0];
        }
    }
}

// ---------------- launch ----------------
extern "C" void kernel_launch(void* const* d_in, const int* in_sizes, int n_in,
                              void* d_out, int out_size, void* d_ws, size_t ws_size,
                              hipStream_t stream) {
    const float* x   = (const float*)d_in[0];
    const int*   ei  = (const int*)d_in[1];
    const float* W1  = (const float*)d_in[2];
    const float* as1 = (const float*)d_in[3];
    const float* ad1 = (const float*)d_in[4];
    const float* b1  = (const float*)d_in[5];
    const float* W2  = (const float*)d_in[6];
    const float* as2 = (const float*)d_in[7];
    const float* ad2 = (const float*)d_in[8];
    const float* b2  = (const float*)d_in[9];
    const float* Wl  = (const float*)d_in[10];
    const float* bl  = (const float*)d_in[11];
    float* out = (float*)d_out;

    const int* srcp = ei;
    const int* dstp = ei + NE;

    char* w = (char*)d_ws;
    int*   edge_src = (int*)w;  w += (size_t)ET*4;          //  6.8 MB
    f16*   hb       = (f16*)w;  w += (size_t)NN*64*2;       // 12.8 MB
    int*   binbuf   = (int*)w;  w += (size_t)NB*CAP*4;      //  8.0 MB
    int2*  rd       = (int2*)w; w += (size_t)NN*8;          // packed {rowst, deg}
    float* ssrc     = (float*)w; w += (size_t)NN*4;
    float* sdst     = (float*)w; w += (size_t)NN*4;
    float* ssrc2    = (float*)w; w += (size_t)NN*4;
    float* sdst2    = (float*)w; w += (size_t)NN*4;
    float* gsc      = (float*)w; w += (size_t)NN*4;
    float* w2v      = (float*)w; w += (size_t)192*4;        // {W2@a_src2, W2@a_dst2, W2@Wl}
    int*   bcnt     = (int*)w;  w += (size_t)NB*BST*4;

    const int nbA = (NN/2 + 3)/4;           // 12500: 4 waves/block, 2 nodes/wave

    // 1: w2v precompute + bcnt zero
    k_pre2<<<1, 256, 0, stream>>>(W2, as2, ad2, Wl, w2v, bcnt);
    // 2: bin (512 blocks: 2/CU)
    k_bin<<<NBIN, 256, 0, stream>>>(srcp, dstp, bcnt, binbuf);
    // 3: fused CSR dense build || layer-1 gemm (1 tile/wave)
    k_bg<<<NB + NBG, 256, 0, stream>>>(bcnt, binbuf, edge_src, rd,
                                       x, W1, as1, ad1, hb, ssrc, sdst);
    // 4: layer-1 aggregation + fused layer-2 scalar projections
    k_agg1<<<nbA, 256, 0, stream>>>(rd, edge_src, ssrc, sdst, hb, b1,
                                    w2v, ssrc2, sdst2, gsc);
    // 5: layer-2 aggregation (scalar) + final linear
    k_agg2<<<nbA, 256, 0, stream>>>(rd, edge_src, ssrc2, sdst2, gsc,
                                    b2, Wl, bl, out);
}

// Round 18
// 187.680 us; speedup vs baseline: 1.0751x; 1.0751x over previous
//
#include <hip/hip_runtime.h>

#define NN 100000
#define NE 1600000
#define ET (NE + NN)
#define NB 391          // buckets of 256 dst nodes
#define CAP 5120        // slots/bucket (mean 4352, +12 sigma)
#define BST 16          // bcnt pad: 64B per counter
#define NBIN 256        // one block per CU (512 regressed: reservation chain 2x)
#define NCHK (ET/8)     // 212500 8-edge chunks; NE/8 = 200000 boundary
#define NTILE (NN/16)   // 6250 gemm tiles
#define NBG 782         // gemm blocks inside k_bg (1563 regressed: W-setup amortization lost)

typedef _Float16 f16;
typedef __attribute__((ext_vector_type(8))) _Float16 half8;
typedef __attribute__((ext_vector_type(4))) float f32x4;

__device__ __forceinline__ unsigned short hbits(float v){
    f16 h = (f16)v;
    return *(unsigned short*)&h;
}
// pack 2 f32 -> 2 f16 (round-to-zero) in one v_cvt_pk_rtz instruction
__device__ __forceinline__ unsigned pk16(float a, float b){
    auto p = __builtin_amdgcn_cvt_pkrtz(a, b);   // __fp16 ext_vector(2)
    return *(unsigned*)&p;
}
__device__ __forceinline__ float fast_tanh(float x){
    float e = __expf(2.f*x);
    return 1.f - __fdividef(2.f, e + 1.f);
}
// acc_lo += f16(lo half of h2) * a ; acc_hi += f16(hi half of h2) * a
__device__ __forceinline__ void fmix2(float& al, float& ah, unsigned h2, float a){
    asm("v_fma_mix_f32 %0, %2, %3, %0 op_sel_hi:[1,0,0]\n\t"
        "v_fma_mix_f32 %1, %2, %3, %1 op_sel:[1,0,0] op_sel_hi:[1,0,0]"
        : "+v"(al), "+v"(ah) : "v"(h2), "v"(a));
}

// ---------------- pre: w2v = {W2@a_src2, W2@a_dst2, W2@Wl} + zero bcnt ----------------
__global__ void __launch_bounds__(256) k_pre2(const float* __restrict__ W2,
        const float* __restrict__ as2, const float* __restrict__ ad2,
        const float* __restrict__ Wl, float* __restrict__ w2v,
        int* __restrict__ bcnt){
    int t = threadIdx.x;
    if(t < 64){
        float s = 0.f, d = 0.f, g = 0.f;
        #pragma unroll 8
        for(int i=0;i<64;i++){
            float w = W2[t*64 + i];
            s += w*as2[i]; d += w*ad2[i]; g += w*Wl[i];
        }
        w2v[t] = s; w2v[64+t] = d; w2v[128+t] = g;
    }
    for(int i=t;i<NB*BST;i+=256) bcnt[i] = 0;
}

// ---------------- CSR build: bin by dst>>8, vectorized chunk loads ----------------
__global__ void __launch_bounds__(256) k_bin(const int* __restrict__ src,
        const int* __restrict__ dst, int* __restrict__ bcnt,
        int* __restrict__ binbuf){
    __shared__ int cnt[NB];
    __shared__ int cur[NB];
    int t = threadIdx.x;
    for(int i=t;i<NB;i+=256) cnt[i]=0;
    __syncthreads();
    // phase 1: histogram (vector loads of dst)
    for(int g = blockIdx.x*256 + t; g < NCHK; g += NBIN*256){
        if(g < NE/8){
            const uint4* dp = (const uint4*)(dst + g*8);
            uint4 d0 = dp[0], d1 = dp[1];
            atomicAdd(&cnt[d0.x>>8],1); atomicAdd(&cnt[d0.y>>8],1);
            atomicAdd(&cnt[d0.z>>8],1); atomicAdd(&cnt[d0.w>>8],1);
            atomicAdd(&cnt[d1.x>>8],1); atomicAdd(&cnt[d1.y>>8],1);
            atomicAdd(&cnt[d1.z>>8],1); atomicAdd(&cnt[d1.w>>8],1);
        } else {
            int n0 = g*8 - NE;        // 8 consecutive self-loops
            #pragma unroll
            for(int i=0;i<8;i++) atomicAdd(&cnt[(n0+i)>>8],1);
        }
    }
    __syncthreads();
    // phase 2: one global reservation per bucket
    for(int i=t;i<NB;i+=256){ int c=cnt[i]; cur[i] = c ? atomicAdd(&bcnt[i*BST], c) : 0; }
    __syncthreads();
    // phase 3: scatter into reserved runs (vector loads of src+dst)
    for(int g = blockIdx.x*256 + t; g < NCHK; g += NBIN*256){
        int s[8], d[8];
        if(g < NE/8){
            const uint4* sp = (const uint4*)(src + g*8);
            const uint4* dp = (const uint4*)(dst + g*8);
            uint4 s0 = sp[0], s1 = sp[1];
            uint4 d0 = dp[0], d1 = dp[1];
            s[0]=s0.x; s[1]=s0.y; s[2]=s0.z; s[3]=s0.w;
            s[4]=s1.x; s[5]=s1.y; s[6]=s1.z; s[7]=s1.w;
            d[0]=d0.x; d[1]=d0.y; d[2]=d0.z; d[3]=d0.w;
            d[4]=d1.x; d[5]=d1.y; d[6]=d1.z; d[7]=d1.w;
        } else {
            int n0 = g*8 - NE;
            #pragma unroll
            for(int i=0;i<8;i++){ s[i]=n0+i; d[i]=n0+i; }
        }
        #pragma unroll
        for(int i=0;i<8;i++){
            int b = d[i] >> 8;
            int pos = atomicAdd(&cur[b], 1);
            if(pos < CAP) binbuf[b*CAP + pos] = (s[i] << 8) | (d[i] & 255);
        }
    }
}

// ---------------- fused: per-bucket dense CSR build (blocks 0..NB-1)
//                  + layer-1 gemm h=x@W1, ssrc, sdst (blocks NB..NB+NBG-1) ----
__global__ void __launch_bounds__(256) k_bg(
        const int* __restrict__ bcnt, const int* __restrict__ binbuf,
        int* __restrict__ edge_src, int2* __restrict__ rd,
        const float* __restrict__ xin, const float* __restrict__ W,
        const float* __restrict__ avs, const float* __restrict__ avd,
        f16* __restrict__ hb, float* __restrict__ ssrc,
        float* __restrict__ sdst){
    __shared__ int lsrc[CAP];
    __shared__ int ldeg[256], lscan[256], lcur[256], red[256];
    int t = threadIdx.x;
    if(blockIdx.x < NB){
        // ---------- CSR build path ----------
        int b = blockIdx.x;
        int cnt = min(bcnt[b*BST], CAP);
        int part = 0;
        for(int i=t;i<b;i+=256) part += min(bcnt[i*BST], CAP);
        red[t] = part; __syncthreads();
        for(int off=128; off>=1; off>>=1){ if(t<off) red[t]+=red[t+off]; __syncthreads(); }
        int base = red[0];
        __syncthreads();
        ldeg[t] = 0; __syncthreads();
        const int* bb = binbuf + b*CAP;
        for(int i=t;i<cnt;i+=256) atomicAdd(&ldeg[bb[i] & 255], 1);
        __syncthreads();
        int dv = ldeg[t]; lscan[t] = dv; __syncthreads();
        for(int off=1; off<256; off<<=1){
            int u = (t>=off) ? lscan[t-off] : 0;
            __syncthreads(); lscan[t] += u; __syncthreads();
        }
        int excl = lscan[t] - dv; lcur[t] = excl;
        int node = b*256 + t;
        if(node < NN) rd[node] = make_int2(base + excl, dv);
        __syncthreads();
        for(int i=t;i<cnt;i+=256){
            int ent = bb[i];
            int pos = atomicAdd(&lcur[ent & 255], 1);
            lsrc[pos] = ent >> 8;
        }
        __syncthreads();
        for(int i=t;i<cnt;i+=256) edge_src[base+i] = lsrc[i];
    } else {
        // ---------- layer-1 gemm path (fp32 input, f16 MFMA) ----------
        int lane = t & 63;
        int col = lane & 15, q = lane >> 4;
        half8 Bf[2][4];
        #pragma unroll
        for(int kh=0;kh<2;kh++){
            #pragma unroll
            for(int nb=0;nb<4;nb++){
                half8 bfr;
                #pragma unroll
                for(int j=0;j<8;j++){
                    float w = W[(kh*32 + q*8 + j)*64 + nb*16 + col];
                    bfr[j] = (f16)w;
                }
                Bf[kh][nb] = bfr;
            }
        }
        float as[4], ad[4];
        #pragma unroll
        for(int nb=0;nb<4;nb++){ as[nb] = avs[nb*16+col]; ad[nb] = avd[nb*16+col]; }

        int gw = ((blockIdx.x - NB)*256 + t) >> 6;
        int nwaves = NBG*4;
        for(int tile = gw; tile < NTILE; tile += nwaves){
            int n0 = tile*16;
            f32x4 acc[4];
            #pragma unroll
            for(int nb=0;nb<4;nb++) acc[nb] = (f32x4){0.f,0.f,0.f,0.f};
            #pragma unroll
            for(int kh=0;kh<2;kh++){
                const float4* xr = (const float4*)(xin
                                    + (size_t)(n0+col)*64 + kh*32 + q*8);
                float4 u = xr[0], v = xr[1];
                union { half8 h; uint4 u4; } A;
                A.u4.x = pk16(u.x, u.y);
                A.u4.y = pk16(u.z, u.w);
                A.u4.z = pk16(v.x, v.y);
                A.u4.w = pk16(v.z, v.w);
                #pragma unroll
                for(int nb=0;nb<4;nb++)
                    acc[nb] = __builtin_amdgcn_mfma_f32_16x16x32_f16(A.h, Bf[kh][nb], acc[nb], 0,0,0);
            }
            #pragma unroll
            for(int nb=0;nb<4;nb++){
                #pragma unroll
                for(int r=0;r<4;r++)
                    hb[(size_t)(n0 + q*4 + r)*64 + nb*16 + col] = (f16)acc[nb][r];
            }
            #pragma unroll
            for(int r=0;r<4;r++){
                float ps = acc[0][r]*as[0] + acc[1][r]*as[1] + acc[2][r]*as[2] + acc[3][r]*as[3];
                float pd = acc[0][r]*ad[0] + acc[1][r]*ad[1] + acc[2][r]*ad[2] + acc[3][r]*ad[3];
                #pragma unroll
                for(int m=8;m>=1;m>>=1){ ps += __shfl_xor(ps,m); pd += __shfl_xor(pd,m); }
                if(col == 0){ ssrc[n0 + q*4 + r] = ps; sdst[n0 + q*4 + r] = pd; }
            }
        }
    }
}

// ---------------- full-wave fallback (layer 1): one node, any degree ----------------
__device__ __forceinline__ void node_full1(int node, int lane, int2* lp,
        const int2* __restrict__ rd, const int* __restrict__ edge_src,
        const float* __restrict__ ssrc, const float* __restrict__ sdst,
        const f16* __restrict__ hb, const float* __restrict__ bias,
        const float* __restrict__ w2v, float* __restrict__ ssrc2,
        float* __restrict__ sdst2, float* __restrict__ gsc){
    int2 r = rd[node];
    int rs = r.x, d = r.y;
    float sd = sdst[node];
    int g8 = lane >> 3;
    int c  = lane & 7;
    float a0=0.f,a1=0.f,a2=0.f,a3=0.f,a4=0.f,a5=0.f,a6=0.f,a7=0.f;

    float lmax = -1e30f;
    for(int j=lane; j<d; j+=64){
        int sj = edge_src[rs+j];
        float t = ssrc[sj] + sd;
        lmax = fmaxf(lmax, fmaxf(t, 0.2f*t));
    }
    #pragma unroll
    for(int m=32;m>=1;m>>=1) lmax = fmaxf(lmax, __shfl_xor(lmax,m));
    float lsum = 0.f;
    for(int j=lane; j<d; j+=64){
        int sj = edge_src[rs+j];
        float t = ssrc[sj] + sd;
        lsum += __expf(fmaxf(t, 0.2f*t) - lmax);
    }
    #pragma unroll
    for(int m=32;m>=1;m>>=1) lsum += __shfl_xor(lsum,m);
    float inv = 1.0f/(lsum + 1e-16f);
    for(int cb=0; cb<d; cb+=64){
        int s2 = 0; float al = 0.f;
        int j = cb + lane;
        if(j < d){
            s2 = edge_src[rs+j];
            float t = ssrc[s2] + sd;
            al = __expf(fmaxf(t, 0.2f*t) - lmax) * inv;
        }
        lp[lane] = make_int2(__float_as_int(al), s2);
        int dd = min(d - cb, 64);
        for(int i0=0; i0<dd; i0+=16){
            int2 e0 = lp[i0 + g8];
            int2 e1 = lp[i0 + 8 + g8];
            float f0 = __int_as_float(e0.x);
            float f1 = __int_as_float(e1.x);
            uint4 k0 = *(const uint4*)(hb + ((size_t)e0.y<<6) + (c<<3));
            uint4 k1 = *(const uint4*)(hb + ((size_t)e1.y<<6) + (c<<3));
            fmix2(a0,a1,k0.x,f0); fmix2(a2,a3,k0.y,f0);
            fmix2(a4,a5,k0.z,f0); fmix2(a6,a7,k0.w,f0);
            fmix2(a0,a1,k1.x,f1); fmix2(a2,a3,k1.y,f1);
            fmix2(a4,a5,k1.z,f1); fmix2(a6,a7,k1.w,f1);
        }
    }
    #pragma unroll
    for(int m=32;m>=8;m>>=1){
        a0 += __shfl_xor(a0,m); a1 += __shfl_xor(a1,m);
        a2 += __shfl_xor(a2,m); a3 += __shfl_xor(a3,m);
        a4 += __shfl_xor(a4,m); a5 += __shfl_xor(a5,m);
        a6 += __shfl_xor(a6,m); a7 += __shfl_xor(a7,m);
    }
    const float4* bp = (const float4*)bias;
    float4 bv0 = bp[c*2], bv1 = bp[c*2+1];
    float t0 = fast_tanh(a0+bv0.x), t1 = fast_tanh(a1+bv0.y);
    float t2 = fast_tanh(a2+bv0.z), t3 = fast_tanh(a3+bv0.w);
    float t4 = fast_tanh(a4+bv1.x), t5 = fast_tanh(a5+bv1.y);
    float t6 = fast_tanh(a6+bv1.z), t7 = fast_tanh(a7+bv1.w);
    const float4* vs = (const float4*)(w2v);
    const float4* vd = (const float4*)(w2v+64);
    const float4* vg = (const float4*)(w2v+128);
    float4 s0 = vs[c*2], s1 = vs[c*2+1];
    float4 d0 = vd[c*2], d1 = vd[c*2+1];
    float4 g0 = vg[c*2], g1 = vg[c*2+1];
    float q_s = t0*s0.x+t1*s0.y+t2*s0.z+t3*s0.w + t4*s1.x+t5*s1.y+t6*s1.z+t7*s1.w;
    float q_d = t0*d0.x+t1*d0.y+t2*d0.z+t3*d0.w + t4*d1.x+t5*d1.y+t6*d1.z+t7*d1.w;
    float q_g = t0*g0.x+t1*g0.y+t2*g0.z+t3*g0.w + t4*g1.x+t5*g1.y+t6*g1.z+t7*g1.w;
    #pragma unroll
    for(int m=4;m>=1;m>>=1){
        q_s += __shfl_xor(q_s,m); q_d += __shfl_xor(q_d,m); q_g += __shfl_xor(q_g,m);
    }
    if(lane == 0){ ssrc2[node] = q_s; sdst2[node] = q_d; gsc[node] = q_g; }
}

// ---------------- layer-1 aggregation: 2 nodes per wave ----------------
__global__ void __launch_bounds__(256) k_agg1(
        const int2* __restrict__ rd, const int* __restrict__ edge_src,
        const float* __restrict__ ssrc, const float* __restrict__ sdst,
        const f16* __restrict__ hb, const float* __restrict__ bias,
        const float* __restrict__ w2v, float* __restrict__ ssrc2,
        float* __restrict__ sdst2, float* __restrict__ gsc){
    __shared__ int2 pairs[256];
    int tid = threadIdx.x;
    int wv   = (blockIdx.x*256 + tid) >> 6;   // wave id: 0..NN/2-1
    int lane = tid & 63;
    if(wv*2 >= NN) return;
    int2* lp = pairs + (tid & 192);           // wave-private 64-entry table
    int half = lane >> 5, l = lane & 31;
    int node = wv*2 + half;

    int2 r = rd[node];
    int rs = r.x, d = r.y;
    float sd = sdst[node];
    int dmax = max(d, __shfl_xor(d, 32));

    if(dmax <= 32){
        // ---- per-half softmax ----
        int s = 0; float pr = 0.f;
        if(l < d){
            s = edge_src[rs + l];
            float t = ssrc[s] + sd;
            t = fmaxf(t, 0.2f*t);            // leaky_relu
            pr = __expf(fminf(t, 80.f));     // no max-shift: logits O(10)
        }
        float sm = pr;
        #pragma unroll
        for(int m=16;m>=1;m>>=1) sm += __shfl_xor(sm,m);
        float alpha = pr * (1.0f/(sm + 1e-16f));
        lp[lane] = make_int2(__float_as_int(alpha), s);   // lane = half*32+l

        // ---- gather: batch-issue ALL loads, then all FMAs ----
        int g4 = l >> 3;                     // row-group 0..3
        int c  = l & 7;                      // channel chunk
        int base = half << 5;
        int nitw = (dmax + 7) >> 3;          // 1..4, wave-uniform
        float F0[4], F1[4];
        uint4 K0[4], K1[4];
        #pragma unroll
        for(int it=0; it<4; it++){
            if(it < nitw){
                int2 e0 = lp[base + it*8 + g4];
                int2 e1 = lp[base + it*8 + 4 + g4];
                F0[it] = __int_as_float(e0.x);
                F1[it] = __int_as_float(e1.x);
                K0[it] = *(const uint4*)(hb + ((size_t)e0.y<<6) + (c<<3));
                K1[it] = *(const uint4*)(hb + ((size_t)e1.y<<6) + (c<<3));
            }
        }
        float a0=0.f,a1=0.f,a2=0.f,a3=0.f,a4=0.f,a5=0.f,a6=0.f,a7=0.f;
        #pragma unroll
        for(int it=0; it<4; it++){
            if(it < nitw){
                fmix2(a0,a1,K0[it].x,F0[it]); fmix2(a2,a3,K0[it].y,F0[it]);
                fmix2(a4,a5,K0[it].z,F0[it]); fmix2(a6,a7,K0[it].w,F0[it]);
                fmix2(a0,a1,K1[it].x,F1[it]); fmix2(a2,a3,K1[it].y,F1[it]);
                fmix2(a4,a5,K1[it].z,F1[it]); fmix2(a6,a7,K1[it].w,F1[it]);
            }
        }

        // ---- channel-splitting fold over row-groups (lane bits 3,4) ----
        bool b3 = (l >> 3) & 1, b4 = (l >> 4) & 1;
        float u0 = b3 ? a4 : a0, v0 = b3 ? a0 : a4; u0 += __shfl_xor(v0, 8);
        float u1 = b3 ? a5 : a1, v1 = b3 ? a1 : a5; u1 += __shfl_xor(v1, 8);
        float u2 = b3 ? a6 : a2, v2 = b3 ? a2 : a6; u2 += __shfl_xor(v2, 8);
        float u3 = b3 ? a7 : a3, v3 = b3 ? a3 : a7; u3 += __shfl_xor(v3, 8);
        float w0 = b4 ? u2 : u0, z0 = b4 ? u0 : u2; w0 += __shfl_xor(z0, 16);
        float w1 = b4 ? u3 : u1, z1 = b4 ? u1 : u3; w1 += __shfl_xor(z1, 16);
        int ch0 = (c<<3) + ((int)b3<<2) + ((int)b4<<1);   // even; w1 = ch0+1

        // ---- epilogue: tanh + layer-2 scalar dots (replaces t1 store) ----
        float2 bv = ((const float2*)bias)[ch0>>1];
        float tw0 = fast_tanh(w0 + bv.x), tw1 = fast_tanh(w1 + bv.y);
        float2 vs = ((const float2*)(w2v      ))[ch0>>1];
        float2 vd = ((const float2*)(w2v +  64))[ch0>>1];
        float2 vg = ((const float2*)(w2v + 128))[ch0>>1];
        float q_s = tw0*vs.x + tw1*vs.y;
        float q_d = tw0*vd.x + tw1*vd.y;
        float q_g = tw0*vg.x + tw1*vg.y;
        #pragma unroll
        for(int m=16;m>=1;m>>=1){
            q_s += __shfl_xor(q_s,m); q_d += __shfl_xor(q_d,m); q_g += __shfl_xor(q_g,m);
        }
        if(l == 0){ ssrc2[node] = q_s; sdst2[node] = q_d; gsc[node] = q_g; }
    } else {
        // rare: a node with d>32 in this pair -> full-wave generic, twice
        node_full1(wv*2,   lane, lp, rd, edge_src, ssrc, sdst, hb, bias,
                   w2v, ssrc2, sdst2, gsc);
        node_full1(wv*2+1, lane, lp, rd, edge_src, ssrc, sdst, hb, bias,
                   w2v, ssrc2, sdst2, gsc);
    }
}

// ---------------- layer-2 aggregation: scalar ----------------
// out[n] = (sum_j pr_j * g[s_j]) / (sum_j pr_j) + (b2.Wl + bl)
__global__ void __launch_bounds__(256) k_agg2(
        const int2* __restrict__ rd, const int* __restrict__ edge_src,
        const float* __restrict__ ssrc, const float* __restrict__ sdst,
        const float* __restrict__ gsc, const float* __restrict__ bias,
        const float* __restrict__ Wl, const float* __restrict__ bl,
        float* __restrict__ outF){
    int tid = threadIdx.x;
    int wv   = (blockIdx.x*256 + tid) >> 6;
    int lane = tid & 63;
    if(wv*2 >= NN) return;
    int half = lane >> 5, l = lane & 31;
    int node = wv*2 + half;

    // c2 = b2.Wl, computed cooperatively (lane l covers channels 2l, 2l+1)
    float2 bv = ((const float2*)bias)[l];
    float2 wl = ((const float2*)Wl)[l];
    float rc = bv.x*wl.x + bv.y*wl.y;
    #pragma unroll
    for(int m=16;m>=1;m>>=1) rc += __shfl_xor(rc,m);

    int2 r = rd[node];
    int rs = r.x, d = r.y;
    float sd = sdst[node];
    int dmax = max(d, __shfl_xor(d, 32));

    if(dmax <= 32){
        float pr = 0.f, gv = 0.f;
        if(l < d){
            int s = edge_src[rs + l];
            float t = ssrc[s] + sd;
            t = fmaxf(t, 0.2f*t);
            pr = __expf(fminf(t, 80.f));
            gv = gsc[s];
        }
        float sm = pr, num = pr*gv;
        #pragma unroll
        for(int m=16;m>=1;m>>=1){ sm += __shfl_xor(sm,m); num += __shfl_xor(num,m); }
        if(l == 0) outF[node] = num/(sm + 1e-16f) + rc + bl[0];
    } else {
        // rare: full-wave generic with max-shift, both nodes sequentially
        #pragma unroll 1
        for(int k=0;k<2;k++){
            int nd = wv*2 + k;
            int2 r2 = rd[nd];
            int rs2 = r2.x, d2 = r2.y;
            float sd2 = sdst[nd];
            float lmax = -1e30f;
            for(int j=lane; j<d2; j+=64){
                int sj = edge_src[rs2+j];
                float t = ssrc[sj] + sd2;
                lmax = fmaxf(lmax, fmaxf(t, 0.2f*t));
            }
            #pragma unroll
            for(int m=32;m>=1;m>>=1) lmax = fmaxf(lmax, __shfl_xor(lmax,m));
            float lsum = 0.f, lnum = 0.f;
            for(int j=lane; j<d2; j+=64){
                int sj = edge_src[rs2+j];
                float t = ssrc[sj] + sd2;
                float e = __expf(fmaxf(t, 0.2f*t) - lmax);
                lsum += e; lnum += e*gsc[sj];
            }
            #pragma unroll
            for(int m=32;m>=1;m>>=1){ lsum += __shfl_xor(lsum,m); lnum += __shfl_xor(lnum,m); }
            if(lane == 0) outF[nd] = lnum/(lsum + 1e-16f) + rc + bl[0];
        }
    }
}

// ---------------- launch ----------------
extern "C" void kernel_launch(void* const* d_in, const int* in_sizes, int n_in,
                              void* d_out, int out_size, void* d_ws, size_t ws_size,
                              hipStream_t stream) {
    const float* x   = (const float*)d_in[0];
    const int*   ei  = (const int*)d_in[1];
    const float* W1  = (const float*)d_in[2];
    const float* as1 = (const float*)d_in[3];
    const float* ad1 = (const float*)d_in[4];
    const float* b1  = (const float*)d_in[5];
    const float* W2  = (const float*)d_in[6];
    const float* as2 = (const float*)d_in[7];
    const float* ad2 = (const float*)d_in[8];
    const float* b2  = (const float*)d_in[9];
    const float* Wl  = (const float*)d_in[10];
    const float* bl  = (const float*)d_in[11];
    float* out = (float*)d_out;

    const int* srcp = ei;
    const int* dstp = ei + NE;

    char* w = (char*)d_ws;
    int*   edge_src = (int*)w;  w += (size_t)ET*4;          //  6.8 MB
    f16*   hb       = (f16*)w;  w += (size_t)NN*64*2;       // 12.8 MB
    int*   binbuf   = (int*)w;  w += (size_t)NB*CAP*4;      //  8.0 MB
    int2*  rd       = (int2*)w; w += (size_t)NN*8;          // packed {rowst, deg}
    float* ssrc     = (float*)w; w += (size_t)NN*4;
    float* sdst     = (float*)w; w += (size_t)NN*4;
    float* ssrc2    = (float*)w; w += (size_t)NN*4;
    float* sdst2    = (float*)w; w += (size_t)NN*4;
    float* gsc      = (float*)w; w += (size_t)NN*4;
    float* w2v      = (float*)w; w += (size_t)192*4;        // {W2@a_src2, W2@a_dst2, W2@Wl}
    int*   bcnt     = (int*)w;  w += (size_t)NB*BST*4;

    const int nbA = (NN/2 + 3)/4;           // 12500: 4 waves/block, 2 nodes/wave

    // 1: w2v precompute + bcnt zero
    k_pre2<<<1, 256, 0, stream>>>(W2, as2, ad2, Wl, w2v, bcnt);
    // 2: bin
    k_bin<<<NBIN, 256, 0, stream>>>(srcp, dstp, bcnt, binbuf);
    // 3: fused CSR dense build || layer-1 gemm
    k_bg<<<NB + NBG, 256, 0, stream>>>(bcnt, binbuf, edge_src, rd,
                                       x, W1, as1, ad1, hb, ssrc, sdst);
    // 4: layer-1 aggregation + fused layer-2 scalar projections
    k_agg1<<<nbA, 256, 0, stream>>>(rd, edge_src, ssrc, sdst, hb, b1,
                                    w2v, ssrc2, sdst2, gsc);
    // 5: layer-2 aggregation (scalar) + final linear
    k_agg2<<<nbA, 256, 0, stream>>>(rd, edge_src, ssrc2, sdst2, gsc,
                                    b2, Wl, bl, out);
}